// Round 6
// baseline (615.007 us; speedup 1.0000x reference)
//
#include <hip/hip_runtime.h>
#include <float.h>

// x: (B=64, C=256, H=64, W=64) fp32; top-8 per batch over C*H*W; out [B,8,C+3].
#define BB    64
#define CC    256
#define HH    64
#define WW    64
#define K     8
#define NPB   (CC * HH * WW)        // 1048576 elems/batch (2^20)
#define TPB   256
#define OUTC  (CC + 3)              // 259
#define CAP   4096                  // candidate slots per batch
#define NBLK  32                    // filter blocks per batch
#define CHUNK (NPB / NBLK)          // 32768 elems = 8192 float4 per block
#define SBLK  4                     // sample blocks per batch
#define WF4   2048                  // float4 per wave sub-chunk (8192/4 waves)
#define SLABS 8                     // 8 slabs x 256 f4 (4KB) per wave
#define SLABF4 256                  // float4 per slab

// ---------- helpers ----------

__device__ __forceinline__ bool cand_gt(float v1, int i1, float v2, int i2) {
    return (v1 > v2) || (v1 == v2 && i1 < i2);
}

__device__ __forceinline__ void insert8(float nv, int ni, float (&v)[K], int (&ix)[K]) {
    bool gt[K];
#pragma unroll
    for (int p = 0; p < K; ++p) gt[p] = cand_gt(nv, ni, v[p], ix[p]);
#pragma unroll
    for (int p = K - 1; p > 0; --p) {
        if (gt[p - 1]) { v[p] = v[p - 1]; ix[p] = ix[p - 1]; }
    }
#pragma unroll
    for (int p = 0; p < K; ++p) {
        if (gt[p] && (p == 0 || !gt[p - 1])) { v[p] = nv; ix[p] = ni; }
    }
}

__device__ __forceinline__ void insertv8(float nv, float (&v)[K]) {
    bool gt[K];
#pragma unroll
    for (int p = 0; p < K; ++p) gt[p] = (nv > v[p]);
#pragma unroll
    for (int p = K - 1; p > 0; --p) {
        if (gt[p - 1]) v[p] = v[p - 1];
    }
#pragma unroll
    for (int p = 0; p < K; ++p) {
        if (gt[p] && (p == 0 || !gt[p - 1])) v[p] = nv;
    }
}

__device__ __forceinline__ void merge_shfl(int d, float (&v)[K], int (&ix)[K]) {
    float ov[K]; int oi[K];
#pragma unroll
    for (int p = 0; p < K; ++p) {
        ov[p] = __shfl_xor(v[p], d, 64);
        oi[p] = __shfl_xor(ix[p], d, 64);
    }
    float mv[K]; int mi[K];
#pragma unroll
    for (int p = 0; p < K; ++p) {
        bool a = cand_gt(v[p], ix[p], ov[K - 1 - p], oi[K - 1 - p]);
        mv[p] = a ? v[p] : ov[K - 1 - p];
        mi[p] = a ? ix[p] : oi[K - 1 - p];
    }
#pragma unroll
    for (int dd = 4; dd >= 1; dd >>= 1) {
#pragma unroll
        for (int i = 0; i < K; ++i) {
            if ((i & dd) == 0) {
                int j = i + dd;
                if (cand_gt(mv[j], mi[j], mv[i], mi[i])) {
                    float tv = mv[i]; mv[i] = mv[j]; mv[j] = tv;
                    int   ti = mi[i]; mi[i] = mi[j]; mi[j] = ti;
                }
            }
        }
    }
#pragma unroll
    for (int p = 0; p < K; ++p) { v[p] = mv[p]; ix[p] = mi[p]; }
}

__device__ __forceinline__ void merge_shfl_v(int d, float (&v)[K]) {
    float ov[K];
#pragma unroll
    for (int p = 0; p < K; ++p) ov[p] = __shfl_xor(v[p], d, 64);
    float mv[K];
#pragma unroll
    for (int p = 0; p < K; ++p) mv[p] = fmaxf(v[p], ov[K - 1 - p]);
#pragma unroll
    for (int dd = 4; dd >= 1; dd >>= 1) {
#pragma unroll
        for (int i = 0; i < K; ++i) {
            if ((i & dd) == 0) {
                int j = i + dd;
                float lo = fminf(mv[i], mv[j]);
                mv[i] = fmaxf(mv[i], mv[j]);
                mv[j] = lo;
            }
        }
    }
#pragma unroll
    for (int p = 0; p < K; ++p) v[p] = mv[p];
}

// Monotonic fp32 <-> uint map (order-preserving).
__device__ __forceinline__ unsigned fmap(float f) {
    unsigned u = __float_as_uint(f);
    return u ^ ((u & 0x80000000u) ? 0xFFFFFFFFu : 0x80000000u);
}
__device__ __forceinline__ float funmap(unsigned u) {
    u ^= ((u & 0x80000000u) ? 0x80000000u : 0xFFFFFFFFu);
    return __uint_as_float(u);
}

// async global->LDS DMA, 16B per lane per call (m97 path). lds dest must be
// wave-uniform (HW writes base + lane*16); gsrc is per-lane.
__device__ __forceinline__ void gload_lds16(const float4* gsrc, float4* lds_base) {
    __builtin_amdgcn_global_load_lds(
        (const __attribute__((address_space(1))) void*)gsrc,
        (__attribute__((address_space(3))) void*)lds_base,
        16, 0, 0);
}

// ---------- kernel 1: per-batch threshold (4 blocks/batch, atomicMax-merged) ----------
__global__ __launch_bounds__(TPB) void sample_thresh(const float* __restrict__ x,
                                                     unsigned* __restrict__ thr_u,
                                                     int* __restrict__ cnt) {
    const int b  = blockIdx.x / SBLK;
    const int sb = blockIdx.x % SBLK;
    const int t  = threadIdx.x;
    if (sb == 0 && t == 0) cnt[b] = 0;

    float v[K];
#pragma unroll
    for (int p = 0; p < K; ++p) v[p] = -FLT_MAX;

    const float4* xb = reinterpret_cast<const float4*>(x + (size_t)b * NPB) + sb * 1024;
    float4 f[4];
#pragma unroll
    for (int j = 0; j < 4; ++j) f[j] = xb[j * TPB + t];
#pragma unroll
    for (int j = 0; j < 4; ++j) {
        if (f[j].x > v[K - 1]) insertv8(f[j].x, v);
        if (f[j].y > v[K - 1]) insertv8(f[j].y, v);
        if (f[j].z > v[K - 1]) insertv8(f[j].z, v);
        if (f[j].w > v[K - 1]) insertv8(f[j].w, v);
    }

    __shared__ float sv[TPB * K];
#pragma unroll
    for (int p = 0; p < K; ++p) sv[p * TPB + t] = v[p];
    __syncthreads();

    if (t < 64) {
        float mv[K];
#pragma unroll
        for (int p = 0; p < K; ++p) mv[p] = -FLT_MAX;
        for (int j = t; j < TPB * K; j += 64) {
            if (sv[j] > mv[K - 1]) insertv8(sv[j], mv);
        }
        merge_shfl_v(1, mv);  merge_shfl_v(2, mv);  merge_shfl_v(4, mv);
        merge_shfl_v(8, mv);  merge_shfl_v(16, mv); merge_shfl_v(32, mv);
        if (t == 0) atomicMax(&thr_u[b], fmap(mv[K - 1]));
    }
}

// ---------- kernel 2: filter via async global->LDS staging ----------
// Per wave: private 2x4KB LDS double buffer, zero barriers. Per slab: issue
// 4x global_load_lds (1KB each) for slab s+1, counted s_waitcnt vmcnt(4)
// (never 0 mid-loop), scan slab s from LDS. DMA loads define no VGPRs, so the
// compiler inserts no hidden waits -> true deep pipeline (~80KB/CU in flight).
__global__ __launch_bounds__(TPB) void filter_cand(const float4* __restrict__ x4,
                                                   const unsigned* __restrict__ thr_u,
                                                   float* __restrict__ cval,
                                                   int* __restrict__ cidx,
                                                   int* __restrict__ cnt) {
    __shared__ float4 sbuf[4][2][SLABF4];         // 4 waves x 2 x 4KB = 32KB

    const int b    = blockIdx.x / NBLK;
    const int blk  = blockIdx.x % NBLK;
    const int t    = threadIdx.x;
    const int w    = t >> 6;
    const int lane = t & 63;
    const float T  = funmap(thr_u[b]);            // block-uniform -> scalar
    const float4* gw = x4 + ((size_t)b * NPB + (size_t)blk * CHUNK) / 4 + w * WF4;
    const int ebase = blk * CHUNK + w * (WF4 * 4);   // elem offset in batch of wave chunk

    // prologue: issue slab 0 into parity 0
#pragma unroll
    for (int c = 0; c < 4; ++c)
        gload_lds16(gw + c * 64 + lane, &sbuf[w][0][c * 64]);

#pragma unroll 1
    for (int s = 0; s < SLABS; ++s) {
        const int par = s & 1;
        if (s < SLABS - 1) {
#pragma unroll
            for (int c = 0; c < 4; ++c)
                gload_lds16(gw + (s + 1) * SLABF4 + c * 64 + lane,
                            &sbuf[w][par ^ 1][c * 64]);
            asm volatile("s_waitcnt vmcnt(4)" ::: "memory");  // slab s landed
        } else {
            asm volatile("s_waitcnt vmcnt(0)" ::: "memory");  // final slab
        }

        // scan slab s: lane reads 4 consecutive float4 (64B stride -> 2-way bank, free)
#pragma unroll
        for (int j = 0; j < 4; ++j) {
            const float4 f = sbuf[w][par][(lane << 2) | j];
            const float m = fmaxf(fmaxf(f.x, f.y), fmaxf(f.z, f.w));
            if (m >= T) {                          // rare (~1/500 per lane-f4)
                const float vals[4] = {f.x, f.y, f.z, f.w};
                const int e0 = ebase + s * (SLABF4 * 4) + ((lane << 2) | j) * 4;
#pragma unroll
                for (int q = 0; q < 4; ++q) {
                    if (vals[q] >= T) {
                        const int o = atomicAdd(&cnt[b], 1);
                        if (o < CAP) {
                            cval[(size_t)b * CAP + o] = vals[q];
                            cidx[(size_t)b * CAP + o] = e0 + q;
                        }
                    }
                }
            }
        }
    }
}

// ---------- kernel 3: exact top-8 over <=CAP candidates; emit output rows ----------
__global__ __launch_bounds__(TPB) void final_select(const float* __restrict__ cval,
                                                    const int* __restrict__ cidx,
                                                    const int* __restrict__ cnt,
                                                    float* __restrict__ out) {
    const int b = blockIdx.x;
    const int t = threadIdx.x;
    const int n = min(cnt[b], CAP);

    float v[K]; int ix[K];
#pragma unroll
    for (int p = 0; p < K; ++p) { v[p] = -FLT_MAX; ix[p] = 0x7fffffff; }
    const float* cv = cval + (size_t)b * CAP;
    const int*   ci = cidx + (size_t)b * CAP;
    for (int j = t; j < n; j += TPB) {
        const float nv = cv[j]; const int ni = ci[j];
        if (cand_gt(nv, ni, v[K - 1], ix[K - 1])) insert8(nv, ni, v, ix);
    }

    // zero this batch's output block (d_out is poisoned)
    float* ob = out + (size_t)b * K * OUTC;
    for (int j = t; j < K * OUTC; j += TPB) ob[j] = 0.0f;

    __shared__ float sv[TPB * K];
    __shared__ int   si[TPB * K];
#pragma unroll
    for (int p = 0; p < K; ++p) { sv[p * TPB + t] = v[p]; si[p * TPB + t] = ix[p]; }
    __syncthreads();

    if (t < 64) {
        float mv[K]; int mi[K];
#pragma unroll
        for (int p = 0; p < K; ++p) { mv[p] = -FLT_MAX; mi[p] = 0x7fffffff; }
        for (int j = t; j < TPB * K; j += 64) {
            const float nv = sv[j]; const int ni = si[j];
            if (cand_gt(nv, ni, mv[K - 1], mi[K - 1])) insert8(nv, ni, mv, mi);
        }
        merge_shfl(1, mv, mi);  merge_shfl(2, mv, mi);  merge_shfl(4, mv, mi);
        merge_shfl(8, mv, mi);  merge_shfl(16, mv, mi); merge_shfl(32, mv, mi);
        if (t == 0) {
#pragma unroll
            for (int r = 0; r < K; ++r) {
                const int idx = mi[r];
                const int c   = idx >> 12;       // /4096
                const int rem = idx & 4095;
                const int yy  = rem >> 6;
                const int xx  = rem & 63;
                float* row = ob + r * OUTC;
                row[c]      = 1.0f;
                row[CC]     = mv[r];
                row[CC + 1] = (float)xx / 63.0f;
                row[CC + 2] = (float)yy / 63.0f;
            }
        }
    }
}

// ---------- launch ----------

extern "C" void kernel_launch(void* const* d_in, const int* in_sizes, int n_in,
                              void* d_out, int out_size, void* d_ws, size_t ws_size,
                              hipStream_t stream) {
    const float* x = (const float*)d_in[0];
    float* out = (float*)d_out;

    // ws layout: cval BB*CAP f32 | cidx BB*CAP i32 | cnt BB i32 | thr_u BB u32
    float*    cval  = (float*)d_ws;
    int*      cidx  = (int*)((char*)d_ws + (size_t)BB * CAP * sizeof(float));
    int*      cnt   = (int*)((char*)d_ws + (size_t)BB * CAP * 8);
    unsigned* thr_u = (unsigned*)((char*)cnt + 256);

    hipMemsetAsync(thr_u, 0, BB * sizeof(unsigned), stream);  // mapped -FLT_MAX
    sample_thresh<<<BB * SBLK, TPB, 0, stream>>>(x, thr_u, cnt);
    filter_cand<<<BB * NBLK, TPB, 0, stream>>>(reinterpret_cast<const float4*>(x),
                                               thr_u, cval, cidx, cnt);
    final_select<<<BB, TPB, 0, stream>>>(cval, cidx, cnt, out);
}

// Round 7
// 214.980 us; speedup vs baseline: 2.8608x; 2.8608x over previous
//
#include <hip/hip_runtime.h>
#include <float.h>

// x: (B=64, C=256, H=64, W=64) fp32; top-8 per batch over C*H*W; out [B,8,C+3].
#define BB    64
#define CC    256
#define HH    64
#define WW    64
#define K     8
#define NPB   (CC * HH * WW)        // 1048576 elems/batch (2^20)
#define TPB   256
#define OUTC  (CC + 3)              // 259
#define CAP   4096                  // candidate slots per batch
#define NBLK  32                    // filter blocks per batch (R2 layout: best measured)
#define CHUNK (NPB / NBLK)          // 32768 elems = 8192 float4 per block
#define VECS  (CHUNK / (TPB * 4))   // 32 float4 per thread

typedef float f4v __attribute__((ext_vector_type(4)));

// ---------- helpers ----------

__device__ __forceinline__ bool cand_gt(float v1, int i1, float v2, int i2) {
    return (v1 > v2) || (v1 == v2 && i1 < i2);
}

__device__ __forceinline__ void insert8(float nv, int ni, float (&v)[K], int (&ix)[K]) {
    bool gt[K];
#pragma unroll
    for (int p = 0; p < K; ++p) gt[p] = cand_gt(nv, ni, v[p], ix[p]);
#pragma unroll
    for (int p = K - 1; p > 0; --p) {
        if (gt[p - 1]) { v[p] = v[p - 1]; ix[p] = ix[p - 1]; }
    }
#pragma unroll
    for (int p = 0; p < K; ++p) {
        if (gt[p] && (p == 0 || !gt[p - 1])) { v[p] = nv; ix[p] = ni; }
    }
}

__device__ __forceinline__ void insertv8(float nv, float (&v)[K]) {
    bool gt[K];
#pragma unroll
    for (int p = 0; p < K; ++p) gt[p] = (nv > v[p]);
#pragma unroll
    for (int p = K - 1; p > 0; --p) {
        if (gt[p - 1]) v[p] = v[p - 1];
    }
#pragma unroll
    for (int p = 0; p < K; ++p) {
        if (gt[p] && (p == 0 || !gt[p - 1])) v[p] = nv;
    }
}

__device__ __forceinline__ void merge_shfl(int d, float (&v)[K], int (&ix)[K]) {
    float ov[K]; int oi[K];
#pragma unroll
    for (int p = 0; p < K; ++p) {
        ov[p] = __shfl_xor(v[p], d, 64);
        oi[p] = __shfl_xor(ix[p], d, 64);
    }
    float mv[K]; int mi[K];
#pragma unroll
    for (int p = 0; p < K; ++p) {
        bool a = cand_gt(v[p], ix[p], ov[K - 1 - p], oi[K - 1 - p]);
        mv[p] = a ? v[p] : ov[K - 1 - p];
        mi[p] = a ? ix[p] : oi[K - 1 - p];
    }
#pragma unroll
    for (int dd = 4; dd >= 1; dd >>= 1) {
#pragma unroll
        for (int i = 0; i < K; ++i) {
            if ((i & dd) == 0) {
                int j = i + dd;
                if (cand_gt(mv[j], mi[j], mv[i], mi[i])) {
                    float tv = mv[i]; mv[i] = mv[j]; mv[j] = tv;
                    int   ti = mi[i]; mi[i] = mi[j]; mi[j] = ti;
                }
            }
        }
    }
#pragma unroll
    for (int p = 0; p < K; ++p) { v[p] = mv[p]; ix[p] = mi[p]; }
}

__device__ __forceinline__ void merge_shfl_v(int d, float (&v)[K]) {
    float ov[K];
#pragma unroll
    for (int p = 0; p < K; ++p) ov[p] = __shfl_xor(v[p], d, 64);
    float mv[K];
#pragma unroll
    for (int p = 0; p < K; ++p) mv[p] = fmaxf(v[p], ov[K - 1 - p]);
#pragma unroll
    for (int dd = 4; dd >= 1; dd >>= 1) {
#pragma unroll
        for (int i = 0; i < K; ++i) {
            if ((i & dd) == 0) {
                int j = i + dd;
                float lo = fminf(mv[i], mv[j]);
                mv[i] = fmaxf(mv[i], mv[j]);
                mv[j] = lo;
            }
        }
    }
#pragma unroll
    for (int p = 0; p < K; ++p) v[p] = mv[p];
}

// ---------- kernel 1: per-batch threshold (8th largest of 16K subset) ----------
__global__ __launch_bounds__(TPB) void sample_thresh(const float* __restrict__ x,
                                                     float* __restrict__ thr,
                                                     int* __restrict__ cnt) {
    const int b = blockIdx.x;
    const int t = threadIdx.x;
    if (t == 0) cnt[b] = 0;

    float v[K];
#pragma unroll
    for (int p = 0; p < K; ++p) v[p] = -FLT_MAX;

    const float4* xb = reinterpret_cast<const float4*>(x + (size_t)b * NPB);
#pragma unroll
    for (int c = 0; c < 16; ++c) {
        const float4 f = xb[c * TPB + t];
        if (f.x > v[K - 1]) insertv8(f.x, v);
        if (f.y > v[K - 1]) insertv8(f.y, v);
        if (f.z > v[K - 1]) insertv8(f.z, v);
        if (f.w > v[K - 1]) insertv8(f.w, v);
    }

    __shared__ float sv[TPB * K];
#pragma unroll
    for (int p = 0; p < K; ++p) sv[p * TPB + t] = v[p];
    __syncthreads();

    if (t < 64) {
        float mv[K];
#pragma unroll
        for (int p = 0; p < K; ++p) mv[p] = -FLT_MAX;
        for (int j = t; j < TPB * K; j += 64) {
            if (sv[j] > mv[K - 1]) insertv8(sv[j], mv);
        }
        merge_shfl_v(1, mv);  merge_shfl_v(2, mv);  merge_shfl_v(4, mv);
        merge_shfl_v(8, mv);  merge_shfl_v(16, mv); merge_shfl_v(32, mv);
        if (t == 0) thr[b] = mv[K - 1];
    }
}

// ---------- kernel 2: R2 structure (best measured) + nontemporal loads ----------
__global__ __launch_bounds__(TPB) void filter_cand(const f4v* __restrict__ x4,
                                                   const float* __restrict__ thr,
                                                   float* __restrict__ cval,
                                                   int* __restrict__ cidx,
                                                   int* __restrict__ cnt) {
    const int b   = blockIdx.x / NBLK;
    const int blk = blockIdx.x % NBLK;
    const int t   = threadIdx.x;
    const float T = thr[b];                      // block-uniform -> scalar
    const f4v* xb = x4 + ((size_t)b * NPB + (size_t)blk * CHUNK) / 4;
    const int base = blk * CHUNK;

#pragma unroll 4
    for (int it = 0; it < VECS; ++it) {
        const f4v f = __builtin_nontemporal_load(xb + it * TPB + t);
        const float m = fmaxf(fmaxf(f.x, f.y), fmaxf(f.z, f.w));
        if (m >= T) {                            // rare: ~1/512 per lane-iter
            const float vals[4] = {f.x, f.y, f.z, f.w};
            const int e0 = base + (it * TPB + t) * 4;
#pragma unroll
            for (int q = 0; q < 4; ++q) {
                if (vals[q] >= T) {
                    const int o = atomicAdd(&cnt[b], 1);
                    if (o < CAP) {
                        cval[(size_t)b * CAP + o] = vals[q];
                        cidx[(size_t)b * CAP + o] = e0 + q;
                    }
                }
            }
        }
    }
}

// ---------- kernel 3: exact top-8 over <=CAP candidates; emit output rows ----------
__global__ __launch_bounds__(TPB) void final_select(const float* __restrict__ cval,
                                                    const int* __restrict__ cidx,
                                                    const int* __restrict__ cnt,
                                                    float* __restrict__ out) {
    const int b = blockIdx.x;
    const int t = threadIdx.x;
    const int n = min(cnt[b], CAP);

    float v[K]; int ix[K];
#pragma unroll
    for (int p = 0; p < K; ++p) { v[p] = -FLT_MAX; ix[p] = 0x7fffffff; }
    const float* cv = cval + (size_t)b * CAP;
    const int*   ci = cidx + (size_t)b * CAP;
    for (int j = t; j < n; j += TPB) {
        const float nv = cv[j]; const int ni = ci[j];
        if (cand_gt(nv, ni, v[K - 1], ix[K - 1])) insert8(nv, ni, v, ix);
    }

    // zero this batch's output block (d_out is poisoned)
    float* ob = out + (size_t)b * K * OUTC;
    for (int j = t; j < K * OUTC; j += TPB) ob[j] = 0.0f;

    __shared__ float sv[TPB * K];
    __shared__ int   si[TPB * K];
#pragma unroll
    for (int p = 0; p < K; ++p) { sv[p * TPB + t] = v[p]; si[p * TPB + t] = ix[p]; }
    __syncthreads();

    if (t < 64) {
        float mv[K]; int mi[K];
#pragma unroll
        for (int p = 0; p < K; ++p) { mv[p] = -FLT_MAX; mi[p] = 0x7fffffff; }
        for (int j = t; j < TPB * K; j += 64) {
            const float nv = sv[j]; const int ni = si[j];
            if (cand_gt(nv, ni, mv[K - 1], mi[K - 1])) insert8(nv, ni, mv, mi);
        }
        merge_shfl(1, mv, mi);  merge_shfl(2, mv, mi);  merge_shfl(4, mv, mi);
        merge_shfl(8, mv, mi);  merge_shfl(16, mv, mi); merge_shfl(32, mv, mi);
        if (t == 0) {
#pragma unroll
            for (int r = 0; r < K; ++r) {
                const int idx = mi[r];
                const int c   = idx >> 12;       // /4096
                const int rem = idx & 4095;
                const int yy  = rem >> 6;
                const int xx  = rem & 63;
                float* row = ob + r * OUTC;
                row[c]      = 1.0f;
                row[CC]     = mv[r];
                row[CC + 1] = (float)xx / 63.0f;
                row[CC + 2] = (float)yy / 63.0f;
            }
        }
    }
}

// ---------- diagnostic: machine-size probe ----------
// 2048 blocks, each busy-spins 1000 realtime ticks (10us @100MHz) then exits.
// No memory traffic. Duration = 10us * ceil(2048 / resident-block-capacity).
// ~256 CUs active -> one generation -> ~10-15us. ~32 CUs -> ~80us.
// Pure diagnostic for this round; removed next round.
__global__ __launch_bounds__(TPB) void probe_cu() {
    const long long t0 = __builtin_amdgcn_s_memrealtime();
    while (__builtin_amdgcn_s_memrealtime() - t0 < 1000) {
        asm volatile("" ::: "memory");
    }
}

// ---------- launch ----------

extern "C" void kernel_launch(void* const* d_in, const int* in_sizes, int n_in,
                              void* d_out, int out_size, void* d_ws, size_t ws_size,
                              hipStream_t stream) {
    const float* x = (const float*)d_in[0];
    float* out = (float*)d_out;

    // ws layout: cval BB*CAP f32 | cidx BB*CAP i32 | cnt BB i32 | thr BB f32
    float* cval = (float*)d_ws;
    int*   cidx = (int*)((char*)d_ws + (size_t)BB * CAP * sizeof(float));
    int*   cnt  = (int*)((char*)d_ws + (size_t)BB * CAP * 8);
    float* thr  = (float*)((char*)cnt + 256);

    sample_thresh<<<BB, TPB, 0, stream>>>(x, thr, cnt);
    filter_cand<<<BB * NBLK, TPB, 0, stream>>>(reinterpret_cast<const f4v*>(x),
                                               thr, cval, cidx, cnt);
    final_select<<<BB, TPB, 0, stream>>>(cval, cidx, cnt, out);
    probe_cu<<<2048, TPB, 0, stream>>>();
}